// Round 11
// baseline (619.569 us; speedup 1.0000x reference)
//
#include <hip/hip_runtime.h>

#define HW_N 16384   // 128*128 pixels
#define CCH  256     // channels
#define KTOP 20
#define NFG  4096
#define NBG  12288
#define NTOT 16384   // fg+bg concatenated rows
#define BPX  64      // pixels per block
#define BCAND 256    // candidates per tile
#define SLICE 4096   // candidates per slot
#define TILES (SLICE / BCAND)   // 16
#define SCAP 16      // f32 survivor stack; LDS 32+16 = 48 KB

typedef __attribute__((ext_vector_type(8))) short short8;      // 8 bf16 (4 VGPRs)
typedef __attribute__((ext_vector_type(4))) float f32x4;

__device__ __forceinline__ unsigned short f2bf(float v) {
    union { float f; unsigned int u; } c; c.f = v;
    unsigned int r = c.u + 0x7fffu + ((c.u >> 16) & 1u);       // RNE
    return (unsigned short)(r >> 16);
}

__device__ __forceinline__ void ins20(float (&lst)[KTOP], float v) {
    if (v > lst[KTOP - 1]) {
        lst[KTOP - 1] = v;
#pragma unroll
        for (int i = KTOP - 1; i >= 1; --i) {
            float a = lst[i - 1], b = lst[i];
            lst[i - 1] = fmaxf(a, b);
            lst[i]     = fminf(a, b);
        }
    }
}

// ---------- prep: transpose + L2-normalize s -> sn_bf16 [16384][256] ----------
__global__ __launch_bounds__(256) void s_prep_kernel(const float* __restrict__ s,
                                                     unsigned short* __restrict__ sn) {
    __shared__ float T[64][261];              // pad 261: <=2-way banks both phases
    const int t  = threadIdx.x;
    const int p0 = blockIdx.x * 64;
#pragma unroll
    for (int pass = 0; pass < 16; ++pass) {
        int c = pass * 16 + (t >> 4);
        float4 v = *reinterpret_cast<const float4*>(&s[(size_t)c * HW_N + p0 + (t & 15) * 4]);
        int px = (t & 15) * 4;
        T[px + 0][c] = v.x; T[px + 1][c] = v.y; T[px + 2][c] = v.z; T[px + 3][c] = v.w;
    }
    __syncthreads();
    const int px = t >> 2, q = t & 3;         // 4 threads per pixel row
    float sum = 0.f;
#pragma unroll 8
    for (int i = 0; i < 64; ++i) { float v = T[px][q * 64 + i]; sum = fmaf(v, v, sum); }
    sum += __shfl_xor(sum, 1);
    sum += __shfl_xor(sum, 2);
    const float scale = 1.0f / fmaxf(sqrtf(sum), 1e-12f);
    uint4* dst = reinterpret_cast<uint4*>(&sn[(size_t)(p0 + px) * CCH + q * 64]);
#pragma unroll
    for (int g = 0; g < 8; ++g) {
        unsigned int vv[4];
#pragma unroll
        for (int h = 0; h < 4; ++h) {
            float a = T[px][q * 64 + g * 8 + h * 2 + 0] * scale;
            float b = T[px][q * 64 + g * 8 + h * 2 + 1] * scale;
            vv[h] = (unsigned)f2bf(a) | ((unsigned)f2bf(b) << 16);
        }
        uint4 wv; wv.x = vv[0]; wv.y = vv[1]; wv.z = vv[2]; wv.w = vv[3];
        dst[g] = wv;
    }
}

// ---------- prep: L2-normalize fg|bg -> cn_bf16 [16384][256] ----------
__global__ __launch_bounds__(256) void c_prep_kernel(const float* __restrict__ fg,
                                                     const float* __restrict__ bg,
                                                     unsigned short* __restrict__ cn) {
    const int row  = blockIdx.x * 4 + (threadIdx.x >> 6);
    const int lane = threadIdx.x & 63;
    const float* src = (row < NFG) ? &fg[(size_t)row * CCH] : &bg[(size_t)(row - NFG) * CCH];
    float4 v = reinterpret_cast<const float4*>(src)[lane];
    float sum = v.x * v.x + v.y * v.y + v.z * v.z + v.w * v.w;
#pragma unroll
    for (int off = 32; off; off >>= 1) sum += __shfl_xor(sum, off);
    const float scale = 1.0f / fmaxf(sqrtf(sum), 1e-12f);
    uint2 wv;
    wv.x = (unsigned)f2bf(v.x * scale) | ((unsigned)f2bf(v.y * scale) << 16);
    wv.y = (unsigned)f2bf(v.z * scale) | ((unsigned)f2bf(v.w * scale) << 16);
    *reinterpret_cast<uint2*>(&cn[(size_t)row * CCH + lane * 4]) = wv;
}

// ---------- fused MFMA GEMM + top-20; permlane transpose + dual-list ILP ----------
// grid 1024 1-D. slot=(bid&7)>>1 (each XCD works ONE 2MB B-slice -> L2-resident).
// launch_bounds (256,2): give the allocator room (R9's (,3) -> 84 VGPR serialized loads)
__global__ __launch_bounds__(256, 2) void score_kernel(
    const unsigned short* __restrict__ sn,   // [16384][256] bf16, normalized
    const unsigned short* __restrict__ cn,   // [16384][256] bf16, normalized
    float* __restrict__ partial)             // [4][16384][20]
{
    __shared__ __align__(16) unsigned short sA[64][256];   // A tile, chunk^(row&15)  32 KB
    __shared__ float stkf[SCAP][256];                      // f32 survivor stacks     16 KB

    const int t    = threadIdx.x;
    const int w    = t >> 6;                  // wave 0..3 -> cand quadrant
    const int l    = t & 63;
    const int lm   = l & 15;
    const int lh   = l >> 4;
    const int bid  = blockIdx.x;
    const int slot = (bid & 7) >> 1;                       // 2 XCDs per slot
    const int p0   = ((bid >> 3) * 2 + (bid & 1)) * BPX;   // pixel-block (bijective)
    const size_t cbase = (size_t)slot * SLICE;

    // stage A once: 64 rows x 32 chunks of 16B, swizzled chunk^(row&15)
    {
        const int row = t >> 2, qg = t & 3;
        const uint4* g = reinterpret_cast<const uint4*>(&sn[(size_t)(p0 + row) * CCH]);
        uint4* d = reinterpret_cast<uint4*>(&sA[row][0]);
#pragma unroll
        for (int i = 0; i < 8; ++i) {
            int chk = qg * 8 + i;
            d[chk ^ (row & 15)] = g[chk];
        }
    }
    __syncthreads();                          // the ONLY barrier before the merge

    // dual top-20 lists: stream-partitioned (alternating) -> exact union top-20;
    // independent insert chains give ~2x ILP on the serial fmax/fmin path.
    float lstA[KTOP], lstB[KTOP];
#pragma unroll
    for (int i = 0; i < KTOP; ++i) { lstA[i] = -1e30f; lstB[i] = -1e30f; }

    for (int nt = 0; nt < TILES; ++nt) {
        f32x4 acc[4][4];                      // acc[n][m]: D[cand-frag n][px-frag m]
#pragma unroll
        for (int n = 0; n < 4; ++n)
#pragma unroll
            for (int m = 0; m < 4; ++m) { f32x4 z = {0.f, 0.f, 0.f, 0.f}; acc[n][m] = z; }

        // per-lane B row pointers (cand = w*64 + n*16 + lm)
        const unsigned short* bp[4];
#pragma unroll
        for (int n = 0; n < 4; ++n)
            bp[n] = cn + (cbase + (size_t)(nt * BCAND + w * 64 + n * 16 + lm)) * CCH;

#pragma unroll 2
        for (int ch = 0; ch < 4; ++ch) {
            // B fragments straight from global (L2-resident slice); no LDS, no barrier
            short8 bfr[2][4];
            const int koff = ch * 64 + lh * 8;
#pragma unroll
            for (int n = 0; n < 4; ++n) {
                bfr[0][n] = *reinterpret_cast<const short8*>(bp[n] + koff);
                bfr[1][n] = *reinterpret_cast<const short8*>(bp[n] + koff + 32);
            }
#pragma unroll
            for (int k32 = 0; k32 < 2; ++k32) {
                short8 af[4];
#pragma unroll
                for (int m = 0; m < 4; ++m) {
                    int row = m * 16 + lm;
                    int chunk = ch * 8 + k32 * 4 + lh;
                    af[m] = *reinterpret_cast<const short8*>(&sA[row][(chunk ^ (row & 15)) * 8]);
                }
                // swapped operands: D[cand][px] (A-frag = cand rows, B-frag = px cols)
#pragma unroll
                for (int n = 0; n < 4; ++n)
#pragma unroll
                    for (int m = 0; m < 4; ++m)
                        acc[n][m] = __builtin_amdgcn_mfma_f32_16x16x32_bf16(bfr[k32][n], af[m], acc[n][m], 0, 0, 0);
            }
        }

        // ---- in-register 4x4 lane-group transpose (pure VALU permlanes) ----
        // after 2 rounds lane (lh,lm) holds only values of its pixel p = lh*16+lm.
        const float th = fminf(lstA[KTOP - 1], lstB[KTOP - 1]);  // valid lower bound of T20
        int cnt = 0;
#pragma unroll
        for (int n = 0; n < 4; ++n)
#pragma unroll
            for (int j = 0; j < 4; ++j) {
                float v0 = acc[n][0][j], v1 = acc[n][1][j];
                float v2 = acc[n][2][j], v3 = acc[n][3][j];
                asm("v_permlane32_swap_b32 %0, %1" : "+v"(v0), "+v"(v2));
                asm("v_permlane32_swap_b32 %0, %1" : "+v"(v1), "+v"(v3));
                asm("v_permlane16_swap_b32 %0, %1" : "+v"(v0), "+v"(v1));
                asm("v_permlane16_swap_b32 %0, %1" : "+v"(v2), "+v"(v3));
                if (nt == 0) {
                    // alternate lists -> two independent chains in flight
                    ins20(lstA, v0); ins20(lstB, v1);
                    ins20(lstA, v2); ins20(lstB, v3);
                } else {
                    float vv[4] = {v0, v1, v2, v3};
#pragma unroll
                    for (int q = 0; q < 4; ++q) {
                        float v = vv[q];
                        if (v > th) {
                            if (cnt < SCAP) { stkf[cnt][t] = v; ++cnt; }
                            else ins20(lstA, v);           // overflow -> substream A (exact)
                        }
                    }
                }
            }
        if (nt != 0) {
            for (int e = 0; __any(e < cnt); ++e) {         // dense drain, alternating lists
                if (e < cnt) {
                    float v = stkf[e][t];
                    if (e & 1) ins20(lstB, v); else ins20(lstA, v);
                }
            }
        }
    }

    // merge lstB into lstA (B sorted desc -> early break), then cross-wave merge
    {
#pragma unroll
        for (int i = 0; i < KTOP; ++i) {
            float v = lstB[i];
            if (v <= lstA[KTOP - 1]) break;
            ins20(lstA, v);
        }
    }
    __syncthreads();
    float* ml = reinterpret_cast<float*>(&sA[0][0]);       // [4][64][20] alias sA
#pragma unroll
    for (int i = 0; i < KTOP; ++i) ml[(w * 64 + l) * KTOP + i] = lstA[i];
    __syncthreads();
    if (t < 64) {
        float fin[KTOP];
#pragma unroll
        for (int i = 0; i < KTOP; ++i) fin[i] = ml[t * KTOP + i];
        for (int ww = 1; ww < 4; ++ww) {
#pragma unroll
            for (int i = 0; i < KTOP; ++i) {
                float v = ml[(ww * 64 + t) * KTOP + i];
                if (v <= fin[KTOP - 1]) break;             // source sorted desc
                ins20(fin, v);
            }
        }
        float* dst = &partial[((size_t)slot * HW_N + p0 + t) * KTOP];
#pragma unroll
        for (int i = 0; i < KTOP; ++i) dst[i] = fin[i];
    }
}

// ---------- final cross-slot merge -> means ----------
__global__ void merge_kernel(const float* __restrict__ partial, float* __restrict__ out) {
    int idx  = blockIdx.x * blockDim.x + threadIdx.x;      // 0..32767
    int coll = idx >> 14;                                  // 0=fg, 1=bg
    int p    = idx & (HW_N - 1);
    float lst[KTOP];
#pragma unroll
    for (int i = 0; i < KTOP; ++i) lst[i] = -1e30f;
    int s0 = coll ? 1 : 0, s1 = coll ? 4 : 1;
    for (int sl = s0; sl < s1; ++sl) {
        const float* src = &partial[((size_t)sl * HW_N + p) * KTOP];
#pragma unroll
        for (int i = 0; i < KTOP; ++i) {
            float v = src[i];
            if (v <= lst[KTOP - 1]) break;                 // sorted desc
            ins20(lst, v);
        }
    }
    float sum = 0.f;
#pragma unroll
    for (int i = 0; i < KTOP; ++i) sum += lst[i];
    out[idx] = sum / (float)KTOP;
}

// ---------- launch ----------
extern "C" void kernel_launch(void* const* d_in, const int* in_sizes, int n_in,
                              void* d_out, int out_size, void* d_ws, size_t ws_size,
                              hipStream_t stream) {
    const float* s_feat = (const float*)d_in[0];   // [1,256,128,128]
    const float* fg     = (const float*)d_in[1];   // [4096,256]
    const float* bg     = (const float*)d_in[2];   // [12288,256]
    float* out = (float*)d_out;                    // [2][128][128]

    // ws: partial 5.24MB | sn 8.39MB | cn 8.39MB  (~22 MB total)
    float* partial     = (float*)d_ws;
    unsigned short* sn = (unsigned short*)(partial + (size_t)4 * HW_N * KTOP);
    unsigned short* cn = sn + (size_t)HW_N * CCH;

    s_prep_kernel<<<HW_N / 64, 256, 0, stream>>>(s_feat, sn);
    c_prep_kernel<<<NTOT / 4, 256, 0, stream>>>(fg, bg, cn);

    score_kernel<<<1024, 256, 0, stream>>>(sn, cn, partial);

    merge_kernel<<<(2 * HW_N) / 256, 256, 0, stream>>>(partial, out);
}

// Round 12
// 441.694 us; speedup vs baseline: 1.4027x; 1.4027x over previous
//
#include <hip/hip_runtime.h>

#define HW_N 16384   // 128*128 pixels
#define CCH  256     // channels
#define KTOP 20
#define NFG  4096
#define NBG  12288
#define NTOT 16384   // fg+bg concatenated rows
#define BPX  64      // pixels per block
#define BCAND 256    // candidates per tile
#define SLICE 4096   // candidates per slot
#define TILES (SLICE / BCAND)   // 16
#define SCAP 28      // fp16 survivor stack; 32+32+14+1 KB = 80896 B -> 2 blocks/CU

typedef __attribute__((ext_vector_type(8))) short short8;      // 8 bf16 (4 VGPRs)
typedef __attribute__((ext_vector_type(8))) _Float16 half8;
typedef __attribute__((ext_vector_type(4))) float f32x4;

__device__ __forceinline__ unsigned short f2bf(float v) {
    union { float f; unsigned int u; } c; c.f = v;
    unsigned int r = c.u + 0x7fffu + ((c.u >> 16) & 1u);       // RNE
    return (unsigned short)(r >> 16);
}

__device__ __forceinline__ void ins20(float (&lst)[KTOP], float v) {
    if (v > lst[KTOP - 1]) {
        lst[KTOP - 1] = v;
#pragma unroll
        for (int i = KTOP - 1; i >= 1; --i) {
            float a = lst[i - 1], b = lst[i];
            lst[i - 1] = fmaxf(a, b);
            lst[i]     = fminf(a, b);
        }
    }
}

// ---------- prep: transpose + L2-normalize s -> sn_bf16 [16384][256] ----------
__global__ __launch_bounds__(256) void s_prep_kernel(const float* __restrict__ s,
                                                     unsigned short* __restrict__ sn) {
    __shared__ float T[64][261];              // pad 261: <=2-way banks both phases
    const int t  = threadIdx.x;
    const int p0 = blockIdx.x * 64;
#pragma unroll
    for (int pass = 0; pass < 16; ++pass) {
        int c = pass * 16 + (t >> 4);
        float4 v = *reinterpret_cast<const float4*>(&s[(size_t)c * HW_N + p0 + (t & 15) * 4]);
        int px = (t & 15) * 4;
        T[px + 0][c] = v.x; T[px + 1][c] = v.y; T[px + 2][c] = v.z; T[px + 3][c] = v.w;
    }
    __syncthreads();
    const int px = t >> 2, q = t & 3;         // 4 threads per pixel row
    float sum = 0.f;
#pragma unroll 8
    for (int i = 0; i < 64; ++i) { float v = T[px][q * 64 + i]; sum = fmaf(v, v, sum); }
    sum += __shfl_xor(sum, 1);
    sum += __shfl_xor(sum, 2);
    const float scale = 1.0f / fmaxf(sqrtf(sum), 1e-12f);
    uint4* dst = reinterpret_cast<uint4*>(&sn[(size_t)(p0 + px) * CCH + q * 64]);
#pragma unroll
    for (int g = 0; g < 8; ++g) {
        unsigned int vv[4];
#pragma unroll
        for (int h = 0; h < 4; ++h) {
            float a = T[px][q * 64 + g * 8 + h * 2 + 0] * scale;
            float b = T[px][q * 64 + g * 8 + h * 2 + 1] * scale;
            vv[h] = (unsigned)f2bf(a) | ((unsigned)f2bf(b) << 16);
        }
        uint4 wv; wv.x = vv[0]; wv.y = vv[1]; wv.z = vv[2]; wv.w = vv[3];
        dst[g] = wv;
    }
}

// ---------- prep: L2-normalize fg|bg -> cn_bf16 [16384][256] ----------
__global__ __launch_bounds__(256) void c_prep_kernel(const float* __restrict__ fg,
                                                     const float* __restrict__ bg,
                                                     unsigned short* __restrict__ cn) {
    const int row  = blockIdx.x * 4 + (threadIdx.x >> 6);
    const int lane = threadIdx.x & 63;
    const float* src = (row < NFG) ? &fg[(size_t)row * CCH] : &bg[(size_t)(row - NFG) * CCH];
    float4 v = reinterpret_cast<const float4*>(src)[lane];
    float sum = v.x * v.x + v.y * v.y + v.z * v.z + v.w * v.w;
#pragma unroll
    for (int off = 32; off; off >>= 1) sum += __shfl_xor(sum, off);
    const float scale = 1.0f / fmaxf(sqrtf(sum), 1e-12f);
    uint2 wv;
    wv.x = (unsigned)f2bf(v.x * scale) | ((unsigned)f2bf(v.y * scale) << 16);
    wv.y = (unsigned)f2bf(v.z * scale) | ((unsigned)f2bf(v.w * scale) << 16);
    *reinterpret_cast<uint2*>(&cn[(size_t)row * CCH + lane * 4]) = wv;
}

// ---------- fused MFMA GEMM + top-20 (R7 structure + cross-wave threshold) ----------
// grid 1024 1-D. slot=(bid&7)>>1 (each XCD works ONE 2MB B-slice -> L2-resident).
__global__ __launch_bounds__(256, 2) void score_kernel(
    const unsigned short* __restrict__ sn,   // [16384][256] bf16, normalized
    const unsigned short* __restrict__ cn,   // [16384][256] bf16, normalized
    float* __restrict__ partial)             // [4][16384][20]
{
    __shared__ __align__(16) unsigned short sA[64][256];   // A tile, chunk^(row&15)  32 KB
    __shared__ __align__(16) _Float16 sSim[4][64 * 64];    // per-wave sim buffers    32 KB
    __shared__ _Float16 stk[SCAP][256];                    // per-thread stacks       14 KB
    __shared__ float thrg[4][64];                          // per-wave 20th per pixel  1 KB

    const int t    = threadIdx.x;
    const int w    = t >> 6;                  // wave 0..3 -> cand quadrant
    const int l    = t & 63;
    const int lm   = l & 15;
    const int lh   = l >> 4;
    const int bid  = blockIdx.x;
    const int slot = (bid & 7) >> 1;                       // 2 XCDs per slot
    const int p0   = ((bid >> 3) * 2 + (bid & 1)) * BPX;   // pixel-block (bijective)
    const size_t cbase = (size_t)slot * SLICE;

    // stage A once: 64 rows x 32 chunks of 16B, swizzled chunk^(row&15)
    {
        const int row = t >> 2, qg = t & 3;
        const uint4* g = reinterpret_cast<const uint4*>(&sn[(size_t)(p0 + row) * CCH]);
        uint4* d = reinterpret_cast<uint4*>(&sA[row][0]);
#pragma unroll
        for (int i = 0; i < 8; ++i) {
            int chk = qg * 8 + i;
            d[chk ^ (row & 15)] = g[chk];
        }
    }
    reinterpret_cast<float*>(thrg)[t] = -1e30f;            // init shared thresholds
    __syncthreads();                          // the ONLY barrier before the merge

    float lst[KTOP];
#pragma unroll
    for (int i = 0; i < KTOP; ++i) lst[i] = -1e30f;

    _Float16* sim = &sSim[w][0];

    for (int nt = 0; nt < TILES; ++nt) {
        f32x4 acc[4][4];
#pragma unroll
        for (int m = 0; m < 4; ++m)
#pragma unroll
            for (int n = 0; n < 4; ++n) { f32x4 z = {0.f, 0.f, 0.f, 0.f}; acc[m][n] = z; }

        // per-lane B row pointers for this tile (wave quadrant, cand = w*64+n*16+lm)
        const unsigned short* bp[4];
#pragma unroll
        for (int n = 0; n < 4; ++n)
            bp[n] = cn + (cbase + (size_t)(nt * BCAND + w * 64 + n * 16 + lm)) * CCH;

#pragma unroll 2
        for (int ch = 0; ch < 4; ++ch) {
            // B fragments straight from global (L2-resident slice); no LDS, no barrier
            short8 bfr[2][4];
            const int koff = ch * 64 + lh * 8;
#pragma unroll
            for (int n = 0; n < 4; ++n) {
                bfr[0][n] = *reinterpret_cast<const short8*>(bp[n] + koff);
                bfr[1][n] = *reinterpret_cast<const short8*>(bp[n] + koff + 32);
            }
#pragma unroll
            for (int k32 = 0; k32 < 2; ++k32) {
                short8 af[4];
#pragma unroll
                for (int m = 0; m < 4; ++m) {
                    int row = m * 16 + lm;
                    int chunk = ch * 8 + k32 * 4 + lh;
                    af[m] = *reinterpret_cast<const short8*>(&sA[row][(chunk ^ (row & 15)) * 8]);
                }
#pragma unroll
                for (int m = 0; m < 4; ++m)
#pragma unroll
                    for (int n = 0; n < 4; ++n)
                        acc[m][n] = __builtin_amdgcn_mfma_f32_16x16x32_bf16(af[m], bfr[k32][n], acc[m][n], 0, 0, 0);
            }
        }

        // sim write: wave-private region, [px][cand] fp16, chunk^(px&7) swizzle
#pragma unroll
        for (int m = 0; m < 4; ++m)
#pragma unroll
            for (int n = 0; n < 4; ++n)
#pragma unroll
                for (int j = 0; j < 4; ++j) {
                    int px = m * 16 + lh * 4 + j;          // D row = (l>>4)*4 + j
                    int cand = n * 16 + lm;                // D col = l&15
                    int chunk = cand >> 3;
                    sim[px * 64 + ((chunk ^ (px & 7)) * 8) + (cand & 7)] =
                        (_Float16)acc[m][n][j];
                }
        // scan: lane = pixel, wave's 64-cand quadrant (wave-private -> no barrier)
        if (nt == 0) {
#pragma unroll
            for (int c8 = 0; c8 < 8; ++c8) {
                half8 hv = *reinterpret_cast<const half8*>(&sim[l * 64 + ((c8 ^ (l & 7)) * 8)]);
#pragma unroll
                for (int i = 0; i < 8; ++i) ins20(lst, (float)hv[i]);
            }
        } else {
            // cross-wave shared threshold: max over the 4 waves' 20th for this pixel
            // (valid lower bound of global running 20th -> exact, ~4x fewer survivors)
            float th = lst[KTOP - 1];
            th = fmaxf(th, thrg[0][l]);
            th = fmaxf(th, fmaxf(thrg[1][l], fmaxf(thrg[2][l], thrg[3][l])));
            int cnt = 0;
#pragma unroll
            for (int c8 = 0; c8 < 8; ++c8) {
                half8 hv = *reinterpret_cast<const half8*>(&sim[l * 64 + ((c8 ^ (l & 7)) * 8)]);
#pragma unroll
                for (int i = 0; i < 8; ++i) {
                    float v = (float)hv[i];
                    if (v > th) {
                        if (cnt < SCAP) { stk[cnt][t] = hv[i]; ++cnt; }
                        else ins20(lst, v);                // overflow fallback (exact)
                    }
                }
            }
            for (int e = 0; __any(e < cnt); ++e) {         // dense drain
                if (e < cnt) ins20(lst, (float)stk[e][t]);
            }
        }
        thrg[w][l] = lst[KTOP - 1];           // publish my 20th (monotone, single writer)
    }

    // in-block merge of the 4 per-wave lists (alias sA; frag reads done)
    __syncthreads();
    float* ml = reinterpret_cast<float*>(&sA[0][0]);       // [4][64][20]
#pragma unroll
    for (int i = 0; i < KTOP; ++i) ml[(w * 64 + l) * KTOP + i] = lst[i];
    __syncthreads();
    if (t < 64) {
        float fin[KTOP];
#pragma unroll
        for (int i = 0; i < KTOP; ++i) fin[i] = ml[t * KTOP + i];
        for (int ww = 1; ww < 4; ++ww) {
#pragma unroll
            for (int i = 0; i < KTOP; ++i) {
                float v = ml[(ww * 64 + t) * KTOP + i];
                if (v <= fin[KTOP - 1]) break;             // source sorted desc
                ins20(fin, v);
            }
        }
        float* dst = &partial[((size_t)slot * HW_N + p0 + t) * KTOP];
#pragma unroll
        for (int i = 0; i < KTOP; ++i) dst[i] = fin[i];
    }
}

// ---------- final cross-slot merge -> means ----------
__global__ void merge_kernel(const float* __restrict__ partial, float* __restrict__ out) {
    int idx  = blockIdx.x * blockDim.x + threadIdx.x;      // 0..32767
    int coll = idx >> 14;                                  // 0=fg, 1=bg
    int p    = idx & (HW_N - 1);
    float lst[KTOP];
#pragma unroll
    for (int i = 0; i < KTOP; ++i) lst[i] = -1e30f;
    int s0 = coll ? 1 : 0, s1 = coll ? 4 : 1;
    for (int sl = s0; sl < s1; ++sl) {
        const float* src = &partial[((size_t)sl * HW_N + p) * KTOP];
#pragma unroll
        for (int i = 0; i < KTOP; ++i) {
            float v = src[i];
            if (v <= lst[KTOP - 1]) break;                 // sorted desc
            ins20(lst, v);
        }
    }
    float sum = 0.f;
#pragma unroll
    for (int i = 0; i < KTOP; ++i) sum += lst[i];
    out[idx] = sum / (float)KTOP;
}

// ---------- launch ----------
extern "C" void kernel_launch(void* const* d_in, const int* in_sizes, int n_in,
                              void* d_out, int out_size, void* d_ws, size_t ws_size,
                              hipStream_t stream) {
    const float* s_feat = (const float*)d_in[0];   // [1,256,128,128]
    const float* fg     = (const float*)d_in[1];   // [4096,256]
    const float* bg     = (const float*)d_in[2];   // [12288,256]
    float* out = (float*)d_out;                    // [2][128][128]

    // ws: partial 5.24MB | sn 8.39MB | cn 8.39MB  (~22 MB total)
    float* partial     = (float*)d_ws;
    unsigned short* sn = (unsigned short*)(partial + (size_t)4 * HW_N * KTOP);
    unsigned short* cn = sn + (size_t)HW_N * CCH;

    s_prep_kernel<<<HW_N / 64, 256, 0, stream>>>(s_feat, sn);
    c_prep_kernel<<<NTOT / 4, 256, 0, stream>>>(fg, bg, cn);

    score_kernel<<<1024, 256, 0, stream>>>(sn, cn, partial);

    merge_kernel<<<(2 * HW_N) / 256, 256, 0, stream>>>(partial, out);
}